// Round 4
// baseline (136.751 us; speedup 1.0000x reference)
//
#include <hip/hip_runtime.h>
#include <math.h>

#define L_SEQ 16384
#define H_DIM 1024
#define P_DIM 512
#define N2P   1024
#define KDIM  1024
#define NTILE 32     // KDIM / 32
#define CHUNK 64
#define NCHUNK 256   // L_SEQ / CHUNK

typedef __attribute__((ext_vector_type(8))) short short8;
typedef __attribute__((ext_vector_type(4))) float f32x4;
typedef __attribute__((address_space(3))) const char* lds3_t;

__device__ __forceinline__ unsigned short f2bf(float f){
    unsigned int u = __float_as_uint(f);
    u = (u + 0x7FFFu + ((u >> 16) & 1u)) >> 16;
    return (unsigned short)u;
}
__device__ __forceinline__ float bf2f(unsigned int lo16){
    return __uint_as_float(lo16 << 16);
}

// ---------------- prep ----------------
__global__ void k_prep_lambda(const float* __restrict__ lre, const float* __restrict__ lim,
                              const float* __restrict__ lstep,
                              float* __restrict__ lam, float* __restrict__ coef,
                              float* __restrict__ lpow)
{
    int p = threadIdx.x;
    double step = exp((double)lstep[p]);
    double dr = (double)lre[p], di = (double)lim[p];
    double ar = dr*step, ai = di*step;
    double er = exp(ar);
    double lbr = er*cos(ai), lbi = er*sin(ai);
    lam[2*p] = (float)lbr; lam[2*p+1] = (float)lbi;
    double nr = lbr - 1.0, ni = lbi;
    double d2 = dr*dr + di*di;
    coef[2*p]   = (float)((nr*dr + ni*di)/d2);
    coef[2*p+1] = (float)((ni*dr - nr*di)/d2);
    double xr = lbr, xi = lbi;
    #pragma unroll
    for (int s=0;s<6;s++){ double t = xr*xr - xi*xi; xi = 2.0*xr*xi; xr = t; } // ^64
    lpow[2*p] = (float)xr; lpow[2*p+1] = (float)xi;
}

__global__ __launch_bounds__(256)
void k_prep_BB(const float* __restrict__ B, const float* __restrict__ coef,
               unsigned short* __restrict__ BB)
{
    int i = blockIdx.x*256 + threadIdx.x;   // i = p*H + h
    int p = i >> 10, h = i & 1023;
    float br = B[2*i], bi = B[2*i+1];
    float cr = coef[2*p], ci = coef[2*p+1];
    BB[(size_t)(2*p)*H_DIM + h]   = f2bf(cr*br - ci*bi);
    BB[(size_t)(2*p+1)*H_DIM + h] = f2bf(cr*bi + ci*br);
}

__global__ __launch_bounds__(256)
void k_prep_CC(const float* __restrict__ C, unsigned short* __restrict__ CC)
{
    int i = blockIdx.x*256 + threadIdx.x;   // i = h*P + p
    int h = i >> 9, p = i & 511;
    float cr = C[2*i], ci = C[2*i+1];
    CC[(size_t)h*N2P + 2*p]     = f2bf(2.f*cr);
    CC[(size_t)h*N2P + 2*p + 1] = f2bf(-2.f*ci);
}

__global__ __launch_bounds__(256)
void k_cast(const float4* __restrict__ u, unsigned short* __restrict__ o)
{
    int i = blockIdx.x*256 + threadIdx.x;
    float4 a = u[2*i], b = u[2*i+1];
    union { short8 v; unsigned short s[8]; } r;
    r.s[0]=f2bf(a.x); r.s[1]=f2bf(a.y); r.s[2]=f2bf(a.z); r.s[3]=f2bf(a.w);
    r.s[4]=f2bf(b.x); r.s[5]=f2bf(b.y); r.s[6]=f2bf(b.z); r.s[7]=f2bf(b.w);
    *reinterpret_cast<short8*>(o + (size_t)i*8) = r.v;
}

// ---------------- GEMM: 256x256 tile, BK=32, 4 LDS buffers, depth-3 prefetch -------
// C[M][1024] = A[M][1024]bf16 @ Bm[1024][1024]bf16^T
// EPI=0: store bf16 to Cb. EPI=1: store f32 to Cf with += Dv[col]*bf16(U16).
// LDS: A bufs [4][256][32]bf16 at b*16384; B bufs at 65536 + b*16384.
// Swizzle (2-way, free): physical 16B-chunk = logical ^ ((row>>1)&3).
//   stage source col chunk = (lane&3) ^ ((lane>>3)&3); read chunk = (lane>>4) ^ ((lr>>1)&3).
// Per tile: STAGE(t+3) -> asm vmcnt(12) -> s_barrier -> 12x asm ds_read_b128
//           -> lgkmcnt(0)+sched_barrier -> setprio(1) 32 MFMA setprio(0) -> s_barrier.
// asm ds_read keeps the memory legalizer from inserting vmcnt(0) (rule #18).
template<int EPI>
__global__ __launch_bounds__(512, 2)
void gemm256(const unsigned short* __restrict__ A, const unsigned short* __restrict__ Bm,
             float* __restrict__ Cf, unsigned short* __restrict__ Cb,
             const float* __restrict__ Dv, const unsigned short* __restrict__ U16)
{
    __shared__ char lds[131072];
    const int tid  = threadIdx.x;
    const int lane = tid & 63;
    const int wid  = tid >> 6;
    const int wm = wid >> 2, wn = wid & 3;          // 2(M) x 4(N) waves
    const int wg = ((int)blockIdx.x & 7) * 32 + ((int)blockIdx.x >> 3);  // XCD swizzle
    const int tm = wg >> 2, tn = wg & 3;
    const int lr = lane & 15;

    // staging: lane l of wave wid covers LDS row wid*16+(l>>2) (+128), chunk l&3
    const int srow = wid*16 + (lane >> 2);
    const int scol = (((lane & 3) ^ ((lane >> 3) & 3)) << 3);   // ushort units, pre-swizzled
    const size_t aS0 = (size_t)(tm*256 + srow) * KDIM + scol;
    const size_t bS0 = (size_t)(tn*256 + srow) * KDIM + scol;
    const int ldsW = wid * 1024;

    // reading: byte = row*64 + ((lane>>4)^((lr>>1)&3))*16
    const int kc   = (((lane >> 4) ^ ((lr >> 1) & 3)) << 4);
    const int aOff = (wm*128 + lr)*64 + kc;          // + m*1024 via offset imm
    const int bOff = (wn*64  + lr)*64 + kc;          // + n*1024 via offset imm

#define GLOAD(SRC, DST) __builtin_amdgcn_global_load_lds( \
        (const __attribute__((address_space(1))) void*)(SRC), \
        (__attribute__((address_space(3))) void*)(DST), 16, 0, 0)
#define STAGE_A(tt) do{ int bb_ = ((tt)&3)*16384; \
    const unsigned short* s_ = A + aS0 + (size_t)(tt)*32; \
    GLOAD(s_,                    lds + bb_ + ldsW); \
    GLOAD(s_ + (size_t)128*KDIM, lds + bb_ + 8192 + ldsW); }while(0)
#define STAGE_B(tt) do{ int bb_ = 65536 + ((tt)&3)*16384; \
    const unsigned short* s_ = Bm + bS0 + (size_t)(tt)*32; \
    GLOAD(s_,                    lds + bb_ + ldsW); \
    GLOAD(s_ + (size_t)128*KDIM, lds + bb_ + 8192 + ldsW); }while(0)
#define DSR(D, P, IMM) asm volatile("ds_read_b128 %0, %1 offset:" IMM : "=v"(D) : "v"(P))
#define MFMA(a,b,c) __builtin_amdgcn_mfma_f32_16x16x32_bf16(a,b,c,0,0,0)
#define BAR __builtin_amdgcn_s_barrier()

    short8 af[8], bfr[4];
    f32x4 acc[8][4];
    #pragma unroll
    for (int m=0;m<8;m++)
        #pragma unroll
        for (int n=0;n<4;n++) acc[m][n] = (f32x4){0.f,0.f,0.f,0.f};

    // prologue: 3 tiles deep; FIFO per tile = [A,A',B,B']
    STAGE_A(0); STAGE_B(0); STAGE_A(1); STAGE_B(1); STAGE_A(2); STAGE_B(2);

    for (int t = 0; t < NTILE; ++t) {
        const int sb = (t & 3) * 16384;
        const int tt = (t < NTILE-3) ? t+3 : NTILE-1;  // tail: dummy re-stage keeps vmcnt uniform
        STAGE_A(tt);
        STAGE_B(tt);
        asm volatile("s_waitcnt vmcnt(12)" ::: "memory");   // tile t's 4 loads complete
        BAR;
        lds3_t pa = (lds3_t)(lds + sb + aOff);
        lds3_t pb = (lds3_t)(lds + 65536 + sb + bOff);
        DSR(af[0], pa, "0");    DSR(af[1], pa, "1024");
        DSR(af[2], pa, "2048"); DSR(af[3], pa, "3072");
        DSR(af[4], pa, "4096"); DSR(af[5], pa, "5120");
        DSR(af[6], pa, "6144"); DSR(af[7], pa, "7168");
        DSR(bfr[0], pb, "0");    DSR(bfr[1], pb, "1024");
        DSR(bfr[2], pb, "2048"); DSR(bfr[3], pb, "3072");
        asm volatile("s_waitcnt lgkmcnt(0)" ::: "memory");
        __builtin_amdgcn_sched_barrier(0);
        __builtin_amdgcn_s_setprio(1);
        #pragma unroll
        for (int m=0;m<8;m++){
            acc[m][0] = MFMA(af[m], bfr[0], acc[m][0]);
            acc[m][1] = MFMA(af[m], bfr[1], acc[m][1]);
            acc[m][2] = MFMA(af[m], bfr[2], acc[m][2]);
            acc[m][3] = MFMA(af[m], bfr[3], acc[m][3]);
        }
        __builtin_amdgcn_s_setprio(0);
        BAR;   // nobody stages (t+4) into buffer t&3 until all waves read tile t
    }
    asm volatile("s_waitcnt vmcnt(0)" ::: "memory");  // drain tail dummy prefetches

    const int orow0 = tm*256 + wm*128 + (lane>>4)*4;
    const int ocol0 = tn*256 + wn*64 + lr;
    #pragma unroll
    for (int m=0;m<8;m++){
        #pragma unroll
        for (int n=0;n<4;n++){
            int row = orow0 + m*16, col = ocol0 + n*16;
            #pragma unroll
            for (int j=0;j<4;j++){
                size_t idx = (size_t)(row + j)*N2P + col;
                if (EPI) Cf[idx] = acc[m][n][j] + Dv[col]*bf2f(U16[idx]);
                else     Cb[idx] = f2bf(acc[m][n][j]);
            }
        }
    }
#undef GLOAD
#undef STAGE_A
#undef STAGE_B
#undef DSR
#undef MFMA
#undef BAR
}

// ---------------- scan phase 1: per-(chunk, p) aggregate (Bu in bf16 pairs) -------
__global__ __launch_bounds__(512)
void k_agg(const unsigned int* __restrict__ Bu, const float* __restrict__ lam,
           float* __restrict__ agg)
{
    int p = threadIdx.x, c = blockIdx.x;
    float lrr = lam[2*p], lii = lam[2*p+1];
    float xr = 0.f, xi = 0.f;
    const unsigned int* b2 = Bu + (size_t)c*CHUNK*512 + p;
    #pragma unroll 4
    for (int t=0;t<CHUNK;t++){
        unsigned int b = b2[(size_t)t*512];
        float br = __uint_as_float(b << 16);
        float bi = __uint_as_float(b & 0xffff0000u);
        float tr = lrr*xr - lii*xi + br;
        xi = lrr*xi + lii*xr + bi;
        xr = tr;
    }
    agg[((size_t)c*P_DIM + p)*2]     = xr;
    agg[((size_t)c*P_DIM + p)*2 + 1] = xi;
}

// ---------------- scan phase 2: Kogge-Stone over chunks ---------------------
__global__ __launch_bounds__(256)
void k_scan(const float* __restrict__ agg, const float* __restrict__ lpow,
            float* __restrict__ xinit)
{
    __shared__ float sr[NCHUNK], si[NCHUNK];
    int c = threadIdx.x, p = blockIdx.x;
    float xr = agg[((size_t)c*P_DIM + p)*2];
    float xi = agg[((size_t)c*P_DIM + p)*2 + 1];
    sr[c] = xr; si[c] = xi;
    float wr = lpow[2*p], wi = lpow[2*p+1];
    for (int s=1; s<NCHUNK; s<<=1){
        __syncthreads();
        float ur = 0.f, ui = 0.f;
        if (c >= s){ ur = sr[c-s]; ui = si[c-s]; }
        __syncthreads();
        xr += wr*ur - wi*ui;
        xi += wr*ui + wi*ur;
        sr[c] = xr; si[c] = xi;
        float t = wr*wr - wi*wi; wi = 2.f*wr*wi; wr = t;
    }
    __syncthreads();
    float er = 0.f, ei = 0.f;
    if (c > 0){ er = sr[c-1]; ei = si[c-1]; }
    xinit[((size_t)c*P_DIM + p)*2]     = er;
    xinit[((size_t)c*P_DIM + p)*2 + 1] = ei;
}

// ---------------- scan phase 3: apply + emit bf16 pairs ----------------------
__global__ __launch_bounds__(512)
void k_apply(const unsigned int* __restrict__ Bu, const float* __restrict__ lam,
             const float* __restrict__ xinit, unsigned int* __restrict__ xs)
{
    int p = threadIdx.x, c = blockIdx.x;
    float lrr = lam[2*p], lii = lam[2*p+1];
    float xr = xinit[((size_t)c*P_DIM + p)*2];
    float xi = xinit[((size_t)c*P_DIM + p)*2 + 1];
    const unsigned int* b2 = Bu + (size_t)c*CHUNK*512 + p;
    unsigned int* o = xs + (size_t)c*CHUNK*512 + p;
    #pragma unroll 4
    for (int t=0;t<CHUNK;t++){
        unsigned int b = b2[(size_t)t*512];
        float br = __uint_as_float(b << 16);
        float bi = __uint_as_float(b & 0xffff0000u);
        float tr = lrr*xr - lii*xi + br;
        xi = lrr*xi + lii*xr + bi;
        xr = tr;
        o[(size_t)t*512] = (unsigned int)f2bf(xr) | ((unsigned int)f2bf(xi) << 16);
    }
}

extern "C" void kernel_launch(void* const* d_in, const int* in_sizes, int n_in,
                              void* d_out, int out_size, void* d_ws, size_t ws_size,
                              hipStream_t stream)
{
    const float* u   = (const float*)d_in[0];
    const float* lre = (const float*)d_in[1];
    const float* lim = (const float*)d_in[2];
    const float* B   = (const float*)d_in[3];
    const float* C   = (const float*)d_in[4];
    const float* D   = (const float*)d_in[5];
    const float* ls  = (const float*)d_in[6];
    float* out = (float*)d_out;

    char* w = (char*)d_ws;
    unsigned short* u16  = (unsigned short*)(w + 0);          // 32 MiB
    unsigned short* xs16 = (unsigned short*)(w + 33554432);   // 32 MiB
    unsigned short* Bu16 = (unsigned short*)(w + 67108864);   // 32 MiB
    unsigned short* BB   = (unsigned short*)(w + 100663296);  // 2 MiB
    unsigned short* CC   = (unsigned short*)(w + 102760448);  // 2 MiB
    float* lam   = (float*)(w + 104857600);
    float* coef  = (float*)(w + 104861696);
    float* lpow  = (float*)(w + 104865792);
    float* agg   = (float*)(w + 104869888);                   // 1 MiB
    float* xinit = (float*)(w + 105918464);                   // 1 MiB

    k_prep_lambda<<<1, P_DIM, 0, stream>>>(lre, lim, ls, lam, coef, lpow);
    k_prep_BB<<<(P_DIM*H_DIM)/256, 256, 0, stream>>>(B, coef, BB);
    k_prep_CC<<<(H_DIM*P_DIM)/256, 256, 0, stream>>>(C, CC);
    k_cast<<<(L_SEQ*H_DIM)/(256*8), 256, 0, stream>>>((const float4*)u, u16);

    gemm256<0><<<256, 512, 0, stream>>>(u16, BB, nullptr, Bu16, nullptr, nullptr);

    k_agg<<<NCHUNK, P_DIM, 0, stream>>>((const unsigned int*)Bu16, lam, agg);
    k_scan<<<P_DIM, NCHUNK, 0, stream>>>(agg, lpow, xinit);
    k_apply<<<NCHUNK, P_DIM, 0, stream>>>((const unsigned int*)Bu16, lam, xinit,
                                          (unsigned int*)xs16);

    gemm256<1><<<256, 512, 0, stream>>>(xs16, CC, out, nullptr, D, u16);
}

// Round 5
// 135.503 us; speedup vs baseline: 1.0092x; 1.0092x over previous
//
#include <hip/hip_runtime.h>
#include <math.h>

#define L_SEQ 16384
#define H_DIM 1024
#define P_DIM 512
#define N2P   1024
#define KDIM  1024
#define NTILE 32     // KDIM / 32
#define CHUNK 64
#define NCHUNK 256   // L_SEQ / CHUNK

typedef __attribute__((ext_vector_type(8))) short short8;
typedef __attribute__((ext_vector_type(4))) float f32x4;
typedef __attribute__((address_space(3))) const char* lds3_t;

__device__ __forceinline__ unsigned short f2bf(float f){
    unsigned int u = __float_as_uint(f);
    u = (u + 0x7FFFu + ((u >> 16) & 1u)) >> 16;
    return (unsigned short)u;
}
__device__ __forceinline__ float bf2f(unsigned int lo16){
    return __uint_as_float(lo16 << 16);
}

// ---------------- prep ----------------
__global__ void k_prep_lambda(const float* __restrict__ lre, const float* __restrict__ lim,
                              const float* __restrict__ lstep,
                              float* __restrict__ lam, float* __restrict__ coef,
                              float* __restrict__ lpow)
{
    int p = threadIdx.x;
    double step = exp((double)lstep[p]);
    double dr = (double)lre[p], di = (double)lim[p];
    double ar = dr*step, ai = di*step;
    double er = exp(ar);
    double lbr = er*cos(ai), lbi = er*sin(ai);
    lam[2*p] = (float)lbr; lam[2*p+1] = (float)lbi;
    double nr = lbr - 1.0, ni = lbi;
    double d2 = dr*dr + di*di;
    coef[2*p]   = (float)((nr*dr + ni*di)/d2);
    coef[2*p+1] = (float)((ni*dr - nr*di)/d2);
    double xr = lbr, xi = lbi;
    #pragma unroll
    for (int s=0;s<6;s++){ double t = xr*xr - xi*xi; xi = 2.0*xr*xi; xr = t; } // ^64
    lpow[2*p] = (float)xr; lpow[2*p+1] = (float)xi;
}

__global__ __launch_bounds__(256)
void k_prep_BB(const float* __restrict__ B, const float* __restrict__ coef,
               unsigned short* __restrict__ BB)
{
    int i = blockIdx.x*256 + threadIdx.x;   // i = p*H + h
    int p = i >> 10, h = i & 1023;
    float br = B[2*i], bi = B[2*i+1];
    float cr = coef[2*p], ci = coef[2*p+1];
    BB[(size_t)(2*p)*H_DIM + h]   = f2bf(cr*br - ci*bi);
    BB[(size_t)(2*p+1)*H_DIM + h] = f2bf(cr*bi + ci*br);
}

__global__ __launch_bounds__(256)
void k_prep_CC(const float* __restrict__ C, unsigned short* __restrict__ CC)
{
    int i = blockIdx.x*256 + threadIdx.x;   // i = h*P + p
    int h = i >> 9, p = i & 511;
    float cr = C[2*i], ci = C[2*i+1];
    CC[(size_t)h*N2P + 2*p]     = f2bf(2.f*cr);
    CC[(size_t)h*N2P + 2*p + 1] = f2bf(-2.f*ci);
}

__global__ __launch_bounds__(256)
void k_cast(const float4* __restrict__ u, unsigned short* __restrict__ o)
{
    int i = blockIdx.x*256 + threadIdx.x;
    float4 a = u[2*i], b = u[2*i+1];
    union { short8 v; unsigned short s[8]; } r;
    r.s[0]=f2bf(a.x); r.s[1]=f2bf(a.y); r.s[2]=f2bf(a.z); r.s[3]=f2bf(a.w);
    r.s[4]=f2bf(b.x); r.s[5]=f2bf(b.y); r.s[6]=f2bf(b.z); r.s[7]=f2bf(b.w);
    *reinterpret_cast<short8*>(o + (size_t)i*8) = r.v;
}

// ---------------- GEMM: 256x256 tile, BK=32, 4 LDS buffers, depth-3 prefetch -------
// C[M][1024] = A[M][1024]bf16 @ Bm[1024][1024]bf16^T
// EPI=0: store bf16 to Cb. EPI=1: store f32 to Cf with += Dv[col]*bf16(U16).
// Per tile: STAGE(t+3) -> vmcnt(12) -> BAR -> issue 12 ds_read_b128 ->
//   lgkm(6)  M0: a0-3 x b0-1   (8 MFMA)
//   lgkm(4)  M1: a0-3 x b2-3   (8 MFMA)
//   lgkm(0)  M2: a4-7 x b0-3   (16 MFMA)
// -> BAR.  Counted lgkm overlaps MFMA with in-flight LDS reads (T3 interleave);
// sched_barrier(0) after each wait keeps MFMA from hoisting past it (rule #18).
template<int EPI>
__global__ __launch_bounds__(512, 2)
void gemm256(const unsigned short* __restrict__ A, const unsigned short* __restrict__ Bm,
             float* __restrict__ Cf, unsigned short* __restrict__ Cb,
             const float* __restrict__ Dv, const unsigned short* __restrict__ U16)
{
    __shared__ char lds[131072];
    const int tid  = threadIdx.x;
    const int lane = tid & 63;
    const int wid  = tid >> 6;
    const int wm = wid >> 2, wn = wid & 3;          // 2(M) x 4(N) waves
    const int wg = ((int)blockIdx.x & 7) * 32 + ((int)blockIdx.x >> 3);  // XCD swizzle
    const int tm = wg >> 2, tn = wg & 3;
    const int lr = lane & 15;

    // staging: lane l of wave wid covers LDS row wid*16+(l>>2) (+128), chunk l&3
    const int srow = wid*16 + (lane >> 2);
    const int scol = (((lane & 3) ^ ((lane >> 3) & 3)) << 3);   // ushort units, pre-swizzled
    const size_t aS0 = (size_t)(tm*256 + srow) * KDIM + scol;
    const size_t bS0 = (size_t)(tn*256 + srow) * KDIM + scol;
    const int ldsW = wid * 1024;

    // reading: byte = row*64 + ((lane>>4)^((lr>>1)&3))*16   (2-way, conflict-free)
    const int kc   = (((lane >> 4) ^ ((lr >> 1) & 3)) << 4);
    const int aOff = (wm*128 + lr)*64 + kc;          // + m*1024 via offset imm
    const int bOff = (wn*64  + lr)*64 + kc;          // + n*1024 via offset imm

#define GLOAD(SRC, DST) __builtin_amdgcn_global_load_lds( \
        (const __attribute__((address_space(1))) void*)(SRC), \
        (__attribute__((address_space(3))) void*)(DST), 16, 0, 0)
#define STAGE_A(tt) do{ int bb_ = ((tt)&3)*16384; \
    const unsigned short* s_ = A + aS0 + (size_t)(tt)*32; \
    GLOAD(s_,                    lds + bb_ + ldsW); \
    GLOAD(s_ + (size_t)128*KDIM, lds + bb_ + 8192 + ldsW); }while(0)
#define STAGE_B(tt) do{ int bb_ = 65536 + ((tt)&3)*16384; \
    const unsigned short* s_ = Bm + bS0 + (size_t)(tt)*32; \
    GLOAD(s_,                    lds + bb_ + ldsW); \
    GLOAD(s_ + (size_t)128*KDIM, lds + bb_ + 8192 + ldsW); }while(0)
#define DSR(D, P, IMM) asm volatile("ds_read_b128 %0, %1 offset:" IMM : "=v"(D) : "v"(P))
#define LGKM(N) do{ asm volatile("s_waitcnt lgkmcnt(" #N ")" ::: "memory"); \
                    __builtin_amdgcn_sched_barrier(0); }while(0)
#define MFMA(a,b,c) __builtin_amdgcn_mfma_f32_16x16x32_bf16(a,b,c,0,0,0)
#define BAR __builtin_amdgcn_s_barrier()

    short8 af[8], bfr[4];
    f32x4 acc[8][4];
    #pragma unroll
    for (int m=0;m<8;m++)
        #pragma unroll
        for (int n=0;n<4;n++) acc[m][n] = (f32x4){0.f,0.f,0.f,0.f};

    // prologue: 3 tiles deep; FIFO per tile = [A,A',B,B']
    STAGE_A(0); STAGE_B(0); STAGE_A(1); STAGE_B(1); STAGE_A(2); STAGE_B(2);

    for (int t = 0; t < NTILE; ++t) {
        const int sb = (t & 3) * 16384;
        const int tt = (t < NTILE-3) ? t+3 : NTILE-1;  // tail: dummy re-stage keeps vmcnt uniform
        STAGE_A(tt);
        STAGE_B(tt);
        asm volatile("s_waitcnt vmcnt(12)" ::: "memory");   // tile t's 4 loads complete
        BAR;
        lds3_t pa = (lds3_t)(lds + sb + aOff);
        lds3_t pb = (lds3_t)(lds + 65536 + sb + bOff);
        // issue all 12 reads; waits are counted, not full drains
        DSR(af[0], pa, "0");    DSR(af[1], pa, "1024");
        DSR(af[2], pa, "2048"); DSR(af[3], pa, "3072");
        DSR(bfr[0], pb, "0");    DSR(bfr[1], pb, "1024");
        DSR(bfr[2], pb, "2048"); DSR(bfr[3], pb, "3072");
        DSR(af[4], pa, "4096"); DSR(af[5], pa, "5120");
        DSR(af[6], pa, "6144"); DSR(af[7], pa, "7168");
        // M0: needs first 6 reads (a0-3, b0-1); 6 may remain outstanding
        LGKM(6);
        __builtin_amdgcn_s_setprio(1);
        #pragma unroll
        for (int m=0;m<4;m++){
            acc[m][0] = MFMA(af[m], bfr[0], acc[m][0]);
            acc[m][1] = MFMA(af[m], bfr[1], acc[m][1]);
        }
        __builtin_amdgcn_s_setprio(0);
        // M1: needs b2-3 (first 8); 4 may remain outstanding
        LGKM(4);
        __builtin_amdgcn_s_setprio(1);
        #pragma unroll
        for (int m=0;m<4;m++){
            acc[m][2] = MFMA(af[m], bfr[2], acc[m][2]);
            acc[m][3] = MFMA(af[m], bfr[3], acc[m][3]);
        }
        __builtin_amdgcn_s_setprio(0);
        // M2+M3: needs a4-7 (all)
        LGKM(0);
        __builtin_amdgcn_s_setprio(1);
        #pragma unroll
        for (int m=4;m<8;m++){
            acc[m][0] = MFMA(af[m], bfr[0], acc[m][0]);
            acc[m][1] = MFMA(af[m], bfr[1], acc[m][1]);
            acc[m][2] = MFMA(af[m], bfr[2], acc[m][2]);
            acc[m][3] = MFMA(af[m], bfr[3], acc[m][3]);
        }
        __builtin_amdgcn_s_setprio(0);
        BAR;   // nobody stages (t+4) into buffer t&3 until all waves read tile t
    }
    asm volatile("s_waitcnt vmcnt(0)" ::: "memory");  // drain tail dummy prefetches

    const int orow0 = tm*256 + wm*128 + (lane>>4)*4;
    const int ocol0 = tn*256 + wn*64 + lr;
    #pragma unroll
    for (int m=0;m<8;m++){
        #pragma unroll
        for (int n=0;n<4;n++){
            int row = orow0 + m*16, col = ocol0 + n*16;
            #pragma unroll
            for (int j=0;j<4;j++){
                size_t idx = (size_t)(row + j)*N2P + col;
                if (EPI) Cf[idx] = acc[m][n][j] + Dv[col]*bf2f(U16[idx]);
                else     Cb[idx] = f2bf(acc[m][n][j]);
            }
        }
    }
#undef GLOAD
#undef STAGE_A
#undef STAGE_B
#undef DSR
#undef LGKM
#undef MFMA
#undef BAR
}

// ---------------- scan phase 1: per-(chunk, p) aggregate (Bu in bf16 pairs) -------
__global__ __launch_bounds__(512)
void k_agg(const unsigned int* __restrict__ Bu, const float* __restrict__ lam,
           float* __restrict__ agg)
{
    int p = threadIdx.x, c = blockIdx.x;
    float lrr = lam[2*p], lii = lam[2*p+1];
    float xr = 0.f, xi = 0.f;
    const unsigned int* b2 = Bu + (size_t)c*CHUNK*512 + p;
    #pragma unroll 4
    for (int t=0;t<CHUNK;t++){
        unsigned int b = b2[(size_t)t*512];
        float br = __uint_as_float(b << 16);
        float bi = __uint_as_float(b & 0xffff0000u);
        float tr = lrr*xr - lii*xi + br;
        xi = lrr*xi + lii*xr + bi;
        xr = tr;
    }
    agg[((size_t)c*P_DIM + p)*2]     = xr;
    agg[((size_t)c*P_DIM + p)*2 + 1] = xi;
}

// ---------------- scan phase 2: Kogge-Stone over chunks ---------------------
__global__ __launch_bounds__(256)
void k_scan(const float* __restrict__ agg, const float* __restrict__ lpow,
            float* __restrict__ xinit)
{
    __shared__ float sr[NCHUNK], si[NCHUNK];
    int c = threadIdx.x, p = blockIdx.x;
    float xr = agg[((size_t)c*P_DIM + p)*2];
    float xi = agg[((size_t)c*P_DIM + p)*2 + 1];
    sr[c] = xr; si[c] = xi;
    float wr = lpow[2*p], wi = lpow[2*p+1];
    for (int s=1; s<NCHUNK; s<<=1){
        __syncthreads();
        float ur = 0.f, ui = 0.f;
        if (c >= s){ ur = sr[c-s]; ui = si[c-s]; }
        __syncthreads();
        xr += wr*ur - wi*ui;
        xi += wr*ui + wi*ur;
        sr[c] = xr; si[c] = xi;
        float t = wr*wr - wi*wi; wi = 2.f*wr*wi; wr = t;
    }
    __syncthreads();
    float er = 0.f, ei = 0.f;
    if (c > 0){ er = sr[c-1]; ei = si[c-1]; }
    xinit[((size_t)c*P_DIM + p)*2]     = er;
    xinit[((size_t)c*P_DIM + p)*2 + 1] = ei;
}

// ---------------- scan phase 3: apply + emit bf16 pairs ----------------------
__global__ __launch_bounds__(512)
void k_apply(const unsigned int* __restrict__ Bu, const float* __restrict__ lam,
             const float* __restrict__ xinit, unsigned int* __restrict__ xs)
{
    int p = threadIdx.x, c = blockIdx.x;
    float lrr = lam[2*p], lii = lam[2*p+1];
    float xr = xinit[((size_t)c*P_DIM + p)*2];
    float xi = xinit[((size_t)c*P_DIM + p)*2 + 1];
    const unsigned int* b2 = Bu + (size_t)c*CHUNK*512 + p;
    unsigned int* o = xs + (size_t)c*CHUNK*512 + p;
    #pragma unroll 4
    for (int t=0;t<CHUNK;t++){
        unsigned int b = b2[(size_t)t*512];
        float br = __uint_as_float(b << 16);
        float bi = __uint_as_float(b & 0xffff0000u);
        float tr = lrr*xr - lii*xi + br;
        xi = lrr*xi + lii*xr + bi;
        xr = tr;
        o[(size_t)t*512] = (unsigned int)f2bf(xr) | ((unsigned int)f2bf(xi) << 16);
    }
}

extern "C" void kernel_launch(void* const* d_in, const int* in_sizes, int n_in,
                              void* d_out, int out_size, void* d_ws, size_t ws_size,
                              hipStream_t stream)
{
    const float* u   = (const float*)d_in[0];
    const float* lre = (const float*)d_in[1];
    const float* lim = (const float*)d_in[2];
    const float* B   = (const float*)d_in[3];
    const float* C   = (const float*)d_in[4];
    const float* D   = (const float*)d_in[5];
    const float* ls  = (const float*)d_in[6];
    float* out = (float*)d_out;

    char* w = (char*)d_ws;
    unsigned short* u16  = (unsigned short*)(w + 0);          // 32 MiB
    unsigned short* xs16 = (unsigned short*)(w + 33554432);   // 32 MiB
    unsigned short* Bu16 = (unsigned short*)(w + 67108864);   // 32 MiB
    unsigned short* BB   = (unsigned short*)(w + 100663296);  // 2 MiB
    unsigned short* CC   = (unsigned short*)(w + 102760448);  // 2 MiB
    float* lam   = (float*)(w + 104857600);
    float* coef  = (float*)(w + 104861696);
    float* lpow  = (float*)(w + 104865792);
    float* agg   = (float*)(w + 104869888);                   // 1 MiB
    float* xinit = (float*)(w + 105918464);                   // 1 MiB

    k_prep_lambda<<<1, P_DIM, 0, stream>>>(lre, lim, ls, lam, coef, lpow);
    k_prep_BB<<<(P_DIM*H_DIM)/256, 256, 0, stream>>>(B, coef, BB);
    k_prep_CC<<<(H_DIM*P_DIM)/256, 256, 0, stream>>>(C, CC);
    k_cast<<<(L_SEQ*H_DIM)/(256*8), 256, 0, stream>>>((const float4*)u, u16);

    gemm256<0><<<256, 512, 0, stream>>>(u16, BB, nullptr, Bu16, nullptr, nullptr);

    k_agg<<<NCHUNK, P_DIM, 0, stream>>>((const unsigned int*)Bu16, lam, agg);
    k_scan<<<P_DIM, NCHUNK, 0, stream>>>(agg, lpow, xinit);
    k_apply<<<NCHUNK, P_DIM, 0, stream>>>((const unsigned int*)Bu16, lam, xinit,
                                          (unsigned int*)xs16);

    gemm256<1><<<256, 512, 0, stream>>>(xs16, CC, out, nullptr, D, u16);
}

// Round 6
// 134.631 us; speedup vs baseline: 1.0157x; 1.0065x over previous
//
#include <hip/hip_runtime.h>
#include <math.h>

#define L_SEQ 16384
#define H_DIM 1024
#define P_DIM 512
#define N2P   1024
#define KDIM  1024
#define NKT   16     // KDIM / 64 K-tiles
#define CHUNK 64
#define NCHUNK 256   // L_SEQ / CHUNK

typedef __attribute__((ext_vector_type(8))) short short8;
typedef __attribute__((ext_vector_type(4))) float f32x4;
typedef __attribute__((address_space(3))) const char* lds3_t;

__device__ __forceinline__ unsigned short f2bf(float f){
    unsigned int u = __float_as_uint(f);
    u = (u + 0x7FFFu + ((u >> 16) & 1u)) >> 16;
    return (unsigned short)u;
}
__device__ __forceinline__ float bf2f(unsigned int lo16){
    return __uint_as_float(lo16 << 16);
}

// ---------------- prep ----------------
__global__ void k_prep_lambda(const float* __restrict__ lre, const float* __restrict__ lim,
                              const float* __restrict__ lstep,
                              float* __restrict__ lam, float* __restrict__ coef,
                              float* __restrict__ lpow)
{
    int p = threadIdx.x;
    double step = exp((double)lstep[p]);
    double dr = (double)lre[p], di = (double)lim[p];
    double ar = dr*step, ai = di*step;
    double er = exp(ar);
    double lbr = er*cos(ai), lbi = er*sin(ai);
    lam[2*p] = (float)lbr; lam[2*p+1] = (float)lbi;
    double nr = lbr - 1.0, ni = lbi;
    double d2 = dr*dr + di*di;
    coef[2*p]   = (float)((nr*dr + ni*di)/d2);
    coef[2*p+1] = (float)((ni*dr - nr*di)/d2);
    double xr = lbr, xi = lbi;
    #pragma unroll
    for (int s=0;s<6;s++){ double t = xr*xr - xi*xi; xi = 2.0*xr*xi; xr = t; } // ^64
    lpow[2*p] = (float)xr; lpow[2*p+1] = (float)xi;
}

__global__ __launch_bounds__(256)
void k_prep_BB(const float* __restrict__ B, const float* __restrict__ coef,
               unsigned short* __restrict__ BB)
{
    int i = blockIdx.x*256 + threadIdx.x;   // i = p*H + h
    int p = i >> 10, h = i & 1023;
    float br = B[2*i], bi = B[2*i+1];
    float cr = coef[2*p], ci = coef[2*p+1];
    BB[(size_t)(2*p)*H_DIM + h]   = f2bf(cr*br - ci*bi);
    BB[(size_t)(2*p+1)*H_DIM + h] = f2bf(cr*bi + ci*br);
}

__global__ __launch_bounds__(256)
void k_prep_CC(const float* __restrict__ C, unsigned short* __restrict__ CC)
{
    int i = blockIdx.x*256 + threadIdx.x;   // i = h*P + p
    int h = i >> 9, p = i & 511;
    float cr = C[2*i], ci = C[2*i+1];
    CC[(size_t)h*N2P + 2*p]     = f2bf(2.f*cr);
    CC[(size_t)h*N2P + 2*p + 1] = f2bf(-2.f*ci);
}

__global__ __launch_bounds__(256)
void k_cast(const float4* __restrict__ u, unsigned short* __restrict__ o)
{
    int i = blockIdx.x*256 + threadIdx.x;
    float4 a = u[2*i], b = u[2*i+1];
    union { short8 v; unsigned short s[8]; } r;
    r.s[0]=f2bf(a.x); r.s[1]=f2bf(a.y); r.s[2]=f2bf(a.z); r.s[3]=f2bf(a.w);
    r.s[4]=f2bf(b.x); r.s[5]=f2bf(b.y); r.s[6]=f2bf(b.z); r.s[7]=f2bf(b.w);
    *reinterpret_cast<short8*>(o + (size_t)i*8) = r.v;
}

// ---------------- GEMM: m201-style 8-phase, 256x256 tile, BK=64 ----------------
// C[M][1024] = A[M][1024]bf16 @ Bm[1024][1024]bf16^T
// LDS (128KB): A half-tile slot (kt&1, h) at (kt&1)*65536 + h*16384, [128 rows][64 col bf16];
//              B at +32768. Swizzle: phys 16B-chunk = logical ^ (row&7), both sides.
// Window (K-tile kt) = 4 phases x 16 MFMA; each phase: {ds_reads; stage; [vmcnt]; BAR;
//   lgkm(0)+sched_barrier; setprio(1); 16 MFMA; setprio(0); BAR}.
// Stage stream: q1,q2: A(kt+1,0/1); q4: B(kt+2,0)+B(kt+2,1); vmcnt(4) at q4 only
// (retires A(kt+1)+B(kt+1), leaves B(kt+2) in flight). Slot-safety: A(kt+1) slot freed
// q4(kt-1).bar2; B(kt+2) slot freed q3(kt).bar2. Never drains to 0 in the loop.
template<int EPI>
__global__ __launch_bounds__(512, 2)
void gemm256(const unsigned short* __restrict__ A, const unsigned short* __restrict__ Bm,
             float* __restrict__ Cf, unsigned short* __restrict__ Cb,
             const float* __restrict__ Dv, const unsigned short* __restrict__ U16)
{
    __shared__ char lds[131072];
    const int tid  = threadIdx.x;
    const int lane = tid & 63;
    const int wid  = tid >> 6;
    const int wm = wid >> 2, wn = wid & 3;          // 2(M) x 4(N) waves
    const int wg = ((int)blockIdx.x & 7) * 32 + ((int)blockIdx.x >> 3);  // XCD swizzle
    const int tm = wg >> 2, tn = wg & 3;
    const int lr = lane & 15;

    // staging: thread covers half-tile row tid>>3 (+64 on 2nd load), 16B chunk tid&7.
    // gload dst is linear; source col pre-swizzled: logical chunk = (tid&7)^(row&7).
    const int scol = ((tid & 7) ^ ((tid >> 3) & 7)) << 3;   // ushort units
    const int srow = tid >> 3;                               // 0..63
    // reads: row = 16*frag + lr; byte = row*128 + ((g|4ks)^(lr&7))*16, g=lane>>4
    const int kc0 = (((lane >> 4)      ^ (lr & 7)) << 4);
    const int kc1 = ((((lane >> 4) | 4) ^ (lr & 7)) << 4);
    const int aSub = wm*16384 + lr*128;
    const int bSub = 32768 + (wn >> 1)*16384 + (wn & 1)*8192 + lr*128;

#define GLOAD(SRC, DST) __builtin_amdgcn_global_load_lds( \
        (const __attribute__((address_space(1))) void*)(SRC), \
        (__attribute__((address_space(3))) void*)(DST), 16, 0, 0)
#define STAGE_A(kt_, h_) do{ \
    char* d_ = lds + (((kt_)&1)<<16) + (h_)*16384 + tid*16; \
    const unsigned short* s_ = A + (size_t)(tm*256 + (h_)*128 + srow)*KDIM + (size_t)(kt_)*64 + scol; \
    GLOAD(s_, d_); GLOAD(s_ + (size_t)64*KDIM, d_ + 8192); }while(0)
#define STAGE_B(kt_, h_) do{ \
    char* d_ = lds + (((kt_)&1)<<16) + 32768 + (h_)*16384 + tid*16; \
    const unsigned short* s_ = Bm + (size_t)(tn*256 + (h_)*128 + srow)*KDIM + (size_t)(kt_)*64 + scol; \
    GLOAD(s_, d_); GLOAD(s_ + (size_t)64*KDIM, d_ + 8192); }while(0)
#define DSR(D, P, IMM) asm volatile("ds_read_b128 %0, %1 offset:" IMM : "=v"(D) : "v"(P))
#define LGKM0 do{ asm volatile("s_waitcnt lgkmcnt(0)" ::: "memory"); \
                  __builtin_amdgcn_sched_barrier(0); }while(0)
#define VMC4  asm volatile("s_waitcnt vmcnt(4)" ::: "memory")
#define MFMA(a,b,c) __builtin_amdgcn_mfma_f32_16x16x32_bf16(a,b,c,0,0,0)
#define BAR __builtin_amdgcn_s_barrier()
#define PRIO1 __builtin_amdgcn_s_setprio(1)
#define PRIO0 __builtin_amdgcn_s_setprio(0)

    short8 a1[4], a2[4], bb0[4], bb1[4];
    f32x4 acc[8][4];
    #pragma unroll
    for (int m=0;m<8;m++)
        #pragma unroll
        for (int n=0;n<4;n++) acc[m][n] = (f32x4){0.f,0.f,0.f,0.f};

    // prologue: A(0), B(0), B(1); vmcnt(4) keeps B(1) in flight
    STAGE_A(0,0); STAGE_A(0,1); STAGE_B(0,0); STAGE_B(0,1); STAGE_B(1,0); STAGE_B(1,1);
    VMC4; BAR;

    for (int kt = 0; kt < NKT; ++kt) {
        const int sb = (kt & 1) << 16;
        const int tA = (kt+1 < NKT) ? kt+1 : NKT-1;   // tail dummies keep vmcnt uniform
        const int tB = (kt+2 < NKT) ? kt+2 : NKT-1;
        lds3_t pa0 = (lds3_t)(lds + sb + aSub + kc0);
        lds3_t pa1 = (lds3_t)(lds + sb + aSub + kc1);
        lds3_t pb0 = (lds3_t)(lds + sb + bSub + kc0);
        lds3_t pb1 = (lds3_t)(lds + sb + bSub + kc1);

        // ---- q1: m0-3 x n0-3, ks0
        DSR(a1[0], pa0, "0");    DSR(a1[1], pa0, "2048");
        DSR(a1[2], pa0, "4096"); DSR(a1[3], pa0, "6144");
        DSR(bb0[0], pb0, "0");    DSR(bb0[1], pb0, "2048");
        DSR(bb0[2], pb0, "4096"); DSR(bb0[3], pb0, "6144");
        STAGE_A(tA, 0);
        BAR; LGKM0; PRIO1;
        #pragma unroll
        for (int m=0;m<4;m++)
            #pragma unroll
            for (int n=0;n<4;n++) acc[m][n] = MFMA(a1[m], bb0[n], acc[m][n]);
        PRIO0; BAR;

        // ---- q2: m4-7 x n0-3, ks0 (bb0 reused)
        DSR(a2[0], pa0, "8192");  DSR(a2[1], pa0, "10240");
        DSR(a2[2], pa0, "12288"); DSR(a2[3], pa0, "14336");
        STAGE_A(tA, 1);
        BAR; LGKM0; PRIO1;
        #pragma unroll
        for (int m=0;m<4;m++)
            #pragma unroll
            for (int n=0;n<4;n++) acc[4+m][n] = MFMA(a2[m], bb0[n], acc[4+m][n]);
        PRIO0; BAR;

        // ---- q3: m0-3 x n0-3, ks1 (no stage; B(kt) slot frees at this bar2)
        DSR(a1[0], pa1, "0");    DSR(a1[1], pa1, "2048");
        DSR(a1[2], pa1, "4096"); DSR(a1[3], pa1, "6144");
        DSR(bb1[0], pb1, "0");    DSR(bb1[1], pb1, "2048");
        DSR(bb1[2], pb1, "4096"); DSR(bb1[3], pb1, "6144");
        BAR; LGKM0; PRIO1;
        #pragma unroll
        for (int m=0;m<4;m++)
            #pragma unroll
            for (int n=0;n<4;n++) acc[m][n] = MFMA(a1[m], bb1[n], acc[m][n]);
        PRIO0; BAR;

        // ---- q4: m4-7 x n0-3, ks1; stage B(kt+2); counted vmcnt(4)
        DSR(a2[0], pa1, "8192");  DSR(a2[1], pa1, "10240");
        DSR(a2[2], pa1, "12288"); DSR(a2[3], pa1, "14336");
        STAGE_B(tB, 0); STAGE_B(tB, 1);
        VMC4;
        BAR; LGKM0; PRIO1;
        #pragma unroll
        for (int m=0;m<4;m++)
            #pragma unroll
            for (int n=0;n<4;n++) acc[4+m][n] = MFMA(a2[m], bb1[n], acc[4+m][n]);
        PRIO0; BAR;
    }
    asm volatile("s_waitcnt vmcnt(0)" ::: "memory");  // drain tail dummy prefetches

    const int orow0 = tm*256 + wm*128 + (lane>>4)*4;
    const int ocol0 = tn*256 + wn*64 + lr;
    #pragma unroll
    for (int m=0;m<8;m++){
        #pragma unroll
        for (int n=0;n<4;n++){
            int row = orow0 + m*16, col = ocol0 + n*16;
            #pragma unroll
            for (int j=0;j<4;j++){
                size_t idx = (size_t)(row + j)*N2P + col;
                if (EPI) Cf[idx] = acc[m][n][j] + Dv[col]*bf2f(U16[idx]);
                else     Cb[idx] = f2bf(acc[m][n][j]);
            }
        }
    }
#undef GLOAD
#undef STAGE_A
#undef STAGE_B
#undef DSR
#undef LGKM0
#undef VMC4
#undef MFMA
#undef BAR
#undef PRIO1
#undef PRIO0
}

// ---------------- scan phase 1: per-(chunk, p) aggregate (Bu in bf16 pairs) -------
__global__ __launch_bounds__(512)
void k_agg(const unsigned int* __restrict__ Bu, const float* __restrict__ lam,
           float* __restrict__ agg)
{
    int p = threadIdx.x, c = blockIdx.x;
    float lrr = lam[2*p], lii = lam[2*p+1];
    float xr = 0.f, xi = 0.f;
    const unsigned int* b2 = Bu + (size_t)c*CHUNK*512 + p;
    #pragma unroll 4
    for (int t=0;t<CHUNK;t++){
        unsigned int b = b2[(size_t)t*512];
        float br = __uint_as_float(b << 16);
        float bi = __uint_as_float(b & 0xffff0000u);
        float tr = lrr*xr - lii*xi + br;
        xi = lrr*xi + lii*xr + bi;
        xr = tr;
    }
    agg[((size_t)c*P_DIM + p)*2]     = xr;
    agg[((size_t)c*P_DIM + p)*2 + 1] = xi;
}

// ---------------- scan phase 2: Kogge-Stone over chunks ---------------------
__global__ __launch_bounds__(256)
void k_scan(const float* __restrict__ agg, const float* __restrict__ lpow,
            float* __restrict__ xinit)
{
    __shared__ float sr[NCHUNK], si[NCHUNK];
    int c = threadIdx.x, p = blockIdx.x;
    float xr = agg[((size_t)c*P_DIM + p)*2];
    float xi = agg[((size_t)c*P_DIM + p)*2 + 1];
    sr[c] = xr; si[c] = xi;
    float wr = lpow[2*p], wi = lpow[2*p+1];
    for (int s=1; s<NCHUNK; s<<=1){
        __syncthreads();
        float ur = 0.f, ui = 0.f;
        if (c >= s){ ur = sr[c-s]; ui = si[c-s]; }
        __syncthreads();
        xr += wr*ur - wi*ui;
        xi += wr*ui + wi*ur;
        sr[c] = xr; si[c] = xi;
        float t = wr*wr - wi*wi; wi = 2.f*wr*wi; wr = t;
    }
    __syncthreads();
    float er = 0.f, ei = 0.f;
    if (c > 0){ er = sr[c-1]; ei = si[c-1]; }
    xinit[((size_t)c*P_DIM + p)*2]     = er;
    xinit[((size_t)c*P_DIM + p)*2 + 1] = ei;
}

// ---------------- scan phase 3: apply + emit bf16 pairs ----------------------
__global__ __launch_bounds__(512)
void k_apply(const unsigned int* __restrict__ Bu, const float* __restrict__ lam,
             const float* __restrict__ xinit, unsigned int* __restrict__ xs)
{
    int p = threadIdx.x, c = blockIdx.x;
    float lrr = lam[2*p], lii = lam[2*p+1];
    float xr = xinit[((size_t)c*P_DIM + p)*2];
    float xi = xinit[((size_t)c*P_DIM + p)*2 + 1];
    const unsigned int* b2 = Bu + (size_t)c*CHUNK*512 + p;
    unsigned int* o = xs + (size_t)c*CHUNK*512 + p;
    #pragma unroll 4
    for (int t=0;t<CHUNK;t++){
        unsigned int b = b2[(size_t)t*512];
        float br = __uint_as_float(b << 16);
        float bi = __uint_as_float(b & 0xffff0000u);
        float tr = lrr*xr - lii*xi + br;
        xi = lrr*xi + lii*xr + bi;
        xr = tr;
        o[(size_t)t*512] = (unsigned int)f2bf(xr) | ((unsigned int)f2bf(xi) << 16);
    }
}

extern "C" void kernel_launch(void* const* d_in, const int* in_sizes, int n_in,
                              void* d_out, int out_size, void* d_ws, size_t ws_size,
                              hipStream_t stream)
{
    const float* u   = (const float*)d_in[0];
    const float* lre = (const float*)d_in[1];
    const float* lim = (const float*)d_in[2];
    const float* B   = (const float*)d_in[3];
    const float* C   = (const float*)d_in[4];
    const float* D   = (const float*)d_in[5];
    const float* ls  = (const float*)d_in[6];
    float* out = (float*)d_out;

    char* w = (char*)d_ws;
    unsigned short* u16  = (unsigned short*)(w + 0);          // 32 MiB
    unsigned short* xs16 = (unsigned short*)(w + 33554432);   // 32 MiB
    unsigned short* Bu16 = (unsigned short*)(w + 67108864);   // 32 MiB
    unsigned short* BB   = (unsigned short*)(w + 100663296);  // 2 MiB
    unsigned short* CC   = (unsigned short*)(w + 102760448);  // 2 MiB
    float* lam   = (float*)(w + 104857600);
    float* coef  = (float*)(w + 104861696);
    float* lpow  = (float*)(w + 104865792);
    float* agg   = (float*)(w + 104869888);                   // 1 MiB
    float* xinit = (float*)(w + 105918464);                   // 1 MiB

    k_prep_lambda<<<1, P_DIM, 0, stream>>>(lre, lim, ls, lam, coef, lpow);
    k_prep_BB<<<(P_DIM*H_DIM)/256, 256, 0, stream>>>(B, coef, BB);
    k_prep_CC<<<(H_DIM*P_DIM)/256, 256, 0, stream>>>(C, CC);
    k_cast<<<(L_SEQ*H_DIM)/(256*8), 256, 0, stream>>>((const float4*)u, u16);

    gemm256<0><<<256, 512, 0, stream>>>(u16, BB, nullptr, Bu16, nullptr, nullptr);

    k_agg<<<NCHUNK, P_DIM, 0, stream>>>((const unsigned int*)Bu16, lam, agg);
    k_scan<<<P_DIM, NCHUNK, 0, stream>>>(agg, lpow, xinit);
    k_apply<<<NCHUNK, P_DIM, 0, stream>>>((const unsigned int*)Bu16, lam, xinit,
                                          (unsigned int*)xs16);

    gemm256<1><<<256, 512, 0, stream>>>(xs16, CC, out, nullptr, D, u16);
}

// Round 7
// 128.975 us; speedup vs baseline: 1.0603x; 1.0439x over previous
//
#include <hip/hip_runtime.h>
#include <math.h>

#define L_SEQ 16384
#define H_DIM 1024
#define P_DIM 512
#define N2P   1024
#define KDIM  1024
#define NKT   16     // KDIM / 64 K-tiles
#define CHUNK 64
#define NCHUNK 256   // L_SEQ / CHUNK

typedef __attribute__((ext_vector_type(8))) short short8;
typedef __attribute__((ext_vector_type(4))) float f32x4;
typedef __attribute__((address_space(3))) const char* lds3_t;

__device__ __forceinline__ unsigned short f2bf(float f){
    unsigned int u = __float_as_uint(f);
    u = (u + 0x7FFFu + ((u >> 16) & 1u)) >> 16;
    return (unsigned short)u;
}
__device__ __forceinline__ float bf2f(unsigned int lo16){
    return __uint_as_float(lo16 << 16);
}

// ---------------- prep ----------------
__global__ void k_prep_lambda(const float* __restrict__ lre, const float* __restrict__ lim,
                              const float* __restrict__ lstep,
                              float* __restrict__ lam, float* __restrict__ coef,
                              float* __restrict__ lpow)
{
    int p = threadIdx.x;
    double step = exp((double)lstep[p]);
    double dr = (double)lre[p], di = (double)lim[p];
    double ar = dr*step, ai = di*step;
    double er = exp(ar);
    double lbr = er*cos(ai), lbi = er*sin(ai);
    lam[2*p] = (float)lbr; lam[2*p+1] = (float)lbi;
    double nr = lbr - 1.0, ni = lbi;
    double d2 = dr*dr + di*di;
    coef[2*p]   = (float)((nr*dr + ni*di)/d2);
    coef[2*p+1] = (float)((ni*dr - nr*di)/d2);
    double xr = lbr, xi = lbi;
    #pragma unroll
    for (int s=0;s<6;s++){ double t = xr*xr - xi*xi; xi = 2.0*xr*xi; xr = t; } // ^64
    lpow[2*p] = (float)xr; lpow[2*p+1] = (float)xi;
}

__global__ __launch_bounds__(256)
void k_prep_BB(const float* __restrict__ B, const float* __restrict__ coef,
               unsigned short* __restrict__ BB)
{
    int i = blockIdx.x*256 + threadIdx.x;   // i = p*H + h
    int p = i >> 10, h = i & 1023;
    float br = B[2*i], bi = B[2*i+1];
    float cr = coef[2*p], ci = coef[2*p+1];
    BB[(size_t)(2*p)*H_DIM + h]   = f2bf(cr*br - ci*bi);
    BB[(size_t)(2*p+1)*H_DIM + h] = f2bf(cr*bi + ci*br);
}

__global__ __launch_bounds__(256)
void k_prep_CC(const float* __restrict__ C, unsigned short* __restrict__ CC)
{
    int i = blockIdx.x*256 + threadIdx.x;   // i = h*P + p
    int h = i >> 9, p = i & 511;
    float cr = C[2*i], ci = C[2*i+1];
    CC[(size_t)h*N2P + 2*p]     = f2bf(2.f*cr);
    CC[(size_t)h*N2P + 2*p + 1] = f2bf(-2.f*ci);
}

__global__ __launch_bounds__(256)
void k_cast(const float4* __restrict__ u, unsigned short* __restrict__ o)
{
    int i = blockIdx.x*256 + threadIdx.x;
    float4 a = u[2*i], b = u[2*i+1];
    union { short8 v; unsigned short s[8]; } r;
    r.s[0]=f2bf(a.x); r.s[1]=f2bf(a.y); r.s[2]=f2bf(a.z); r.s[3]=f2bf(a.w);
    r.s[4]=f2bf(b.x); r.s[5]=f2bf(b.y); r.s[6]=f2bf(b.z); r.s[7]=f2bf(b.w);
    *reinterpret_cast<short8*>(o + (size_t)i*8) = r.v;
}

// ---------------- GEMM: 256x256, BK=64, 2-KT dbuf, quadrant-pipelined LDS reads ----
// Per K-tile (one C-quadrant per cluster, 16 MFMA each):
//   DSR(Q1:8) STAGE_A(kt+1) DSR(Q2:4)  lgkm(4)  MFMA Q1    <- Q2 reads overlap Q1 MFMA
//   DSR(Q3:8)                          lgkm(8)  MFMA Q2    <- Q3 reads overlap Q2 MFMA
//   DSR(Q4:4)                          lgkm(4)  BAR(mid)
//   STAGE_B(kt+2)                                MFMA Q3   <- Q4 reads already in flight
//                                      lgkm(0)  MFMA Q4
//   vmcnt(4)  BAR(end)
// Counted lgkm = T3/T4 fine interleave; raw asm s_barrier (no legalizer drains);
// mid-BAR legalizes STAGE_B overwriting buf[kt&1].B (all B(kt) reads retired by
// each wave's pre-bar lgkm(4)). vmcnt(4)/KT retires A(kt+1)+B(kt+1), leaves
// B(kt+2) in flight — never drains to 0 in the loop. Tail dummies re-stage
// identical data (value-safe).
template<int EPI>
__global__ __launch_bounds__(512, 2)
void gemm256(const unsigned short* __restrict__ A, const unsigned short* __restrict__ Bm,
             float* __restrict__ Cf, unsigned short* __restrict__ Cb,
             const float* __restrict__ Dv, const unsigned short* __restrict__ U16)
{
    __shared__ char lds[131072];
    const int tid  = threadIdx.x;
    const int lane = tid & 63;
    const int wid  = tid >> 6;
    const int wm = wid >> 2, wn = wid & 3;          // 2(M) x 4(N) waves
    const int wg = ((int)blockIdx.x & 7) * 32 + ((int)blockIdx.x >> 3);  // XCD swizzle
    const int tm = wg >> 2, tn = wg & 3;
    const int lr = lane & 15;

    // staging: thread covers half-tile row tid>>3 (+64 on 2nd load), 16B chunk tid&7.
    // gload dst linear; source col pre-swizzled: logical chunk = (tid&7)^(row&7).
    const int scol = ((tid & 7) ^ ((tid >> 3) & 7)) << 3;   // ushort units
    const int srow = tid >> 3;                               // 0..63
    // reads: row = 16*frag + lr; byte = row*128 + ((g|4ks)^(lr&7))*16, g=lane>>4
    const int kc0 = (((lane >> 4)      ^ (lr & 7)) << 4);
    const int kc1 = ((((lane >> 4) | 4) ^ (lr & 7)) << 4);
    const int aSub = wm*16384 + lr*128;
    const int bSub = 32768 + (wn >> 1)*16384 + (wn & 1)*8192 + lr*128;

#define GLOAD(SRC, DST) __builtin_amdgcn_global_load_lds( \
        (const __attribute__((address_space(1))) void*)(SRC), \
        (__attribute__((address_space(3))) void*)(DST), 16, 0, 0)
#define STAGE_A(kt_, h_) do{ \
    char* d_ = lds + (((kt_)&1)<<16) + (h_)*16384 + tid*16; \
    const unsigned short* s_ = A + (size_t)(tm*256 + (h_)*128 + srow)*KDIM + (size_t)(kt_)*64 + scol; \
    GLOAD(s_, d_); GLOAD(s_ + (size_t)64*KDIM, d_ + 8192); }while(0)
#define STAGE_B(kt_, h_) do{ \
    char* d_ = lds + (((kt_)&1)<<16) + 32768 + (h_)*16384 + tid*16; \
    const unsigned short* s_ = Bm + (size_t)(tn*256 + (h_)*128 + srow)*KDIM + (size_t)(kt_)*64 + scol; \
    GLOAD(s_, d_); GLOAD(s_ + (size_t)64*KDIM, d_ + 8192); }while(0)
#define DSR(D, P, IMM) asm volatile("ds_read_b128 %0, %1 offset:" IMM : "=v"(D) : "v"(P))
#define LGKM(N) do{ asm volatile("s_waitcnt lgkmcnt(" #N ")" ::: "memory"); \
                    __builtin_amdgcn_sched_barrier(0); }while(0)
#define VMC4  asm volatile("s_waitcnt vmcnt(4)" ::: "memory")
#define ABAR  asm volatile("s_barrier" ::: "memory")
#define SB0   __builtin_amdgcn_sched_barrier(0)
#define MFMA(a,b,c) __builtin_amdgcn_mfma_f32_16x16x32_bf16(a,b,c,0,0,0)
#define PRIO1 __builtin_amdgcn_s_setprio(1)
#define PRIO0 __builtin_amdgcn_s_setprio(0)

    short8 a1[4], a2[4], bb0[4], bb1[4];
    f32x4 acc[8][4];
    #pragma unroll
    for (int m=0;m<8;m++)
        #pragma unroll
        for (int n=0;n<4;n++) acc[m][n] = (f32x4){0.f,0.f,0.f,0.f};

    // prologue: A(0), B(0), B(1); vmcnt(4) keeps B(1) in flight
    STAGE_A(0,0); STAGE_A(0,1); STAGE_B(0,0); STAGE_B(0,1); STAGE_B(1,0); STAGE_B(1,1);
    VMC4; ABAR;

    #pragma unroll 2
    for (int kt = 0; kt < NKT; ++kt) {
        const int sb = (kt & 1) << 16;
        const int tA = (kt+1 < NKT) ? kt+1 : NKT-1;   // tail dummies keep vmcnt uniform
        const int tB = (kt+2 < NKT) ? kt+2 : NKT-1;
        lds3_t pa0 = (lds3_t)(lds + sb + aSub + kc0);
        lds3_t pa1 = (lds3_t)(lds + sb + aSub + kc1);
        lds3_t pb0 = (lds3_t)(lds + sb + bSub + kc0);
        lds3_t pb1 = (lds3_t)(lds + sb + bSub + kc1);

        // ---- Q1 reads (8) + A prefetch + Q2 reads (4); lgkm 12 outstanding
        DSR(a1[0], pa0, "0");    DSR(a1[1], pa0, "2048");
        DSR(a1[2], pa0, "4096"); DSR(a1[3], pa0, "6144");
        DSR(bb0[0], pb0, "0");    DSR(bb0[1], pb0, "2048");
        DSR(bb0[2], pb0, "4096"); DSR(bb0[3], pb0, "6144");
        STAGE_A(tA, 0); STAGE_A(tA, 1);
        DSR(a2[0], pa0, "8192");  DSR(a2[1], pa0, "10240");
        DSR(a2[2], pa0, "12288"); DSR(a2[3], pa0, "14336");
        LGKM(4);                 // Q1's 8 done; Q2's 4 in flight under MFMA Q1
        PRIO1;
        #pragma unroll
        for (int m=0;m<4;m++)
            #pragma unroll
            for (int n=0;n<4;n++) acc[m][n] = MFMA(a1[m], bb0[n], acc[m][n]);
        PRIO0; SB0;
        // ---- Q3 reads (8) stream under MFMA Q2
        DSR(a1[0], pa1, "0");    DSR(a1[1], pa1, "2048");
        DSR(a1[2], pa1, "4096"); DSR(a1[3], pa1, "6144");
        DSR(bb1[0], pb1, "0");    DSR(bb1[1], pb1, "2048");
        DSR(bb1[2], pb1, "4096"); DSR(bb1[3], pb1, "6144");
        LGKM(8);                 // Q2's 4 done; Q3's 8 in flight
        PRIO1;
        #pragma unroll
        for (int m=0;m<4;m++)
            #pragma unroll
            for (int n=0;n<4;n++) acc[4+m][n] = MFMA(a2[m], bb0[n], acc[4+m][n]);
        PRIO0; SB0;
        // ---- Q4 reads (4); wait Q3; mid-bar legalizes B-slot overwrite
        DSR(a2[0], pa1, "8192");  DSR(a2[1], pa1, "10240");
        DSR(a2[2], pa1, "12288"); DSR(a2[3], pa1, "14336");
        LGKM(4);                 // Q3's 8 done (all B(kt) reads retired)
        ABAR;                    // mid-KT barrier
        STAGE_B(tB, 0); STAGE_B(tB, 1);
        PRIO1;
        #pragma unroll
        for (int m=0;m<4;m++)
            #pragma unroll
            for (int n=0;n<4;n++) acc[m][n] = MFMA(a1[m], bb1[n], acc[m][n]);
        PRIO0; SB0;
        LGKM(0);                 // Q4's 4 done
        PRIO1;
        #pragma unroll
        for (int m=0;m<4;m++)
            #pragma unroll
            for (int n=0;n<4;n++) acc[4+m][n] = MFMA(a2[m], bb1[n], acc[4+m][n]);
        PRIO0; SB0;
        VMC4;                    // retire A(kt+1)+B(kt+1); B(kt+2) stays in flight
        ABAR;                    // kt-end barrier
    }
    asm volatile("s_waitcnt vmcnt(0)" ::: "memory");  // drain tail dummy prefetches

    const int orow0 = tm*256 + wm*128 + (lane>>4)*4;
    const int ocol0 = tn*256 + wn*64 + lr;
    #pragma unroll
    for (int m=0;m<8;m++){
        #pragma unroll
        for (int n=0;n<4;n++){
            int row = orow0 + m*16, col = ocol0 + n*16;
            #pragma unroll
            for (int j=0;j<4;j++){
                size_t idx = (size_t)(row + j)*N2P + col;
                if (EPI) Cf[idx] = acc[m][n][j] + Dv[col]*bf2f(U16[idx]);
                else     Cb[idx] = f2bf(acc[m][n][j]);
            }
        }
    }
#undef GLOAD
#undef STAGE_A
#undef STAGE_B
#undef DSR
#undef LGKM
#undef VMC4
#undef ABAR
#undef SB0
#undef MFMA
#undef PRIO1
#undef PRIO0
}

// ---------------- scan phase 1: per-(chunk, p) aggregate (Bu in bf16 pairs) -------
__global__ __launch_bounds__(512)
void k_agg(const unsigned int* __restrict__ Bu, const float* __restrict__ lam,
           float* __restrict__ agg)
{
    int p = threadIdx.x, c = blockIdx.x;
    float lrr = lam[2*p], lii = lam[2*p+1];
    float xr = 0.f, xi = 0.f;
    const unsigned int* b2 = Bu + (size_t)c*CHUNK*512 + p;
    #pragma unroll 4
    for (int t=0;t<CHUNK;t++){
        unsigned int b = b2[(size_t)t*512];
        float br = __uint_as_float(b << 16);
        float bi = __uint_as_float(b & 0xffff0000u);
        float tr = lrr*xr - lii*xi + br;
        xi = lrr*xi + lii*xr + bi;
        xr = tr;
    }
    agg[((size_t)c*P_DIM + p)*2]     = xr;
    agg[((size_t)c*P_DIM + p)*2 + 1] = xi;
}

// ---------------- scan phase 2: Kogge-Stone over chunks ---------------------
__global__ __launch_bounds__(256)
void k_scan(const float* __restrict__ agg, const float* __restrict__ lpow,
            float* __restrict__ xinit)
{
    __shared__ float sr[NCHUNK], si[NCHUNK];
    int c = threadIdx.x, p = blockIdx.x;
    float xr = agg[((size_t)c*P_DIM + p)*2];
    float xi = agg[((size_t)c*P_DIM + p)*2 + 1];
    sr[c] = xr; si[c] = xi;
    float wr = lpow[2*p], wi = lpow[2*p+1];
    for (int s=1; s<NCHUNK; s<<=1){
        __syncthreads();
        float ur = 0.f, ui = 0.f;
        if (c >= s){ ur = sr[c-s]; ui = si[c-s]; }
        __syncthreads();
        xr += wr*ur - wi*ui;
        xi += wr*ui + wi*ur;
        sr[c] = xr; si[c] = xi;
        float t = wr*wr - wi*wi; wi = 2.f*wr*wi; wr = t;
    }
    __syncthreads();
    float er = 0.f, ei = 0.f;
    if (c > 0){ er = sr[c-1]; ei = si[c-1]; }
    xinit[((size_t)c*P_DIM + p)*2]     = er;
    xinit[((size_t)c*P_DIM + p)*2 + 1] = ei;
}

// ---------------- scan phase 3: apply + emit bf16 pairs ----------------------
__global__ __launch_bounds__(512)
void k_apply(const unsigned int* __restrict__ Bu, const float* __restrict__ lam,
             const float* __restrict__ xinit, unsigned int* __restrict__ xs)
{
    int p = threadIdx.x, c = blockIdx.x;
    float lrr = lam[2*p], lii = lam[2*p+1];
    float xr = xinit[((size_t)c*P_DIM + p)*2];
    float xi = xinit[((size_t)c*P_DIM + p)*2 + 1];
    const unsigned int* b2 = Bu + (size_t)c*CHUNK*512 + p;
    unsigned int* o = xs + (size_t)c*CHUNK*512 + p;
    #pragma unroll 4
    for (int t=0;t<CHUNK;t++){
        unsigned int b = b2[(size_t)t*512];
        float br = __uint_as_float(b << 16);
        float bi = __uint_as_float(b & 0xffff0000u);
        float tr = lrr*xr - lii*xi + br;
        xi = lrr*xi + lii*xr + bi;
        xr = tr;
        o[(size_t)t*512] = (unsigned int)f2bf(xr) | ((unsigned int)f2bf(xi) << 16);
    }
}

extern "C" void kernel_launch(void* const* d_in, const int* in_sizes, int n_in,
                              void* d_out, int out_size, void* d_ws, size_t ws_size,
                              hipStream_t stream)
{
    const float* u   = (const float*)d_in[0];
    const float* lre = (const float*)d_in[1];
    const float* lim = (const float*)d_in[2];
    const float* B   = (const float*)d_in[3];
    const float* C   = (const float*)d_in[4];
    const float* D   = (const float*)d_in[5];
    const float* ls  = (const float*)d_in[6];
    float* out = (float*)d_out;

    char* w = (char*)d_ws;
    unsigned short* u16  = (unsigned short*)(w + 0);          // 32 MiB
    unsigned short* xs16 = (unsigned short*)(w + 33554432);   // 32 MiB
    unsigned short* Bu16 = (unsigned short*)(w + 67108864);   // 32 MiB
    unsigned short* BB   = (unsigned short*)(w + 100663296);  // 2 MiB
    unsigned short* CC   = (unsigned short*)(w + 102760448);  // 2 MiB
    float* lam   = (float*)(w + 104857600);
    float* coef  = (float*)(w + 104861696);
    float* lpow  = (float*)(w + 104865792);
    float* agg   = (float*)(w + 104869888);                   // 1 MiB
    float* xinit = (float*)(w + 105918464);                   // 1 MiB

    k_prep_lambda<<<1, P_DIM, 0, stream>>>(lre, lim, ls, lam, coef, lpow);
    k_prep_BB<<<(P_DIM*H_DIM)/256, 256, 0, stream>>>(B, coef, BB);
    k_prep_CC<<<(H_DIM*P_DIM)/256, 256, 0, stream>>>(C, CC);
    k_cast<<<(L_SEQ*H_DIM)/(256*8), 256, 0, stream>>>((const float4*)u, u16);

    gemm256<0><<<256, 512, 0, stream>>>(u16, BB, nullptr, Bu16, nullptr, nullptr);

    k_agg<<<NCHUNK, P_DIM, 0, stream>>>((const unsigned int*)Bu16, lam, agg);
    k_scan<<<P_DIM, NCHUNK, 0, stream>>>(agg, lpow, xinit);
    k_apply<<<NCHUNK, P_DIM, 0, stream>>>((const unsigned int*)Bu16, lam, xinit,
                                          (unsigned int*)xs16);

    gemm256<1><<<256, 512, 0, stream>>>(xs16, CC, out, nullptr, D, u16);
}